// Round 5
// baseline (244.717 us; speedup 1.0000x reference)
//
#include <hip/hip_runtime.h>
#include <hip/hip_bf16.h>

// Problem constants
#define BB 2
#define FDIM 2048
#define FH 64
#define FW 128
#define NPIX (FH*FW)        // 8192 pixels per (dom,b)
#define NC 19
#define SH 512
#define SW 1024

// Workspace layout (bytes). sq+cnt+sum need zeroing (atomic accumulation).
#define OFF_SQ    0                         // float sq[2][19]         = 152 B
#define OFF_CNT   152                       // uint  cnt[2][19]        = 152 B
#define OFF_SUM   512                       // float sum[2][19][2048]  = 311296 B
#define ZERO_BYTES 311808
#define OFF_LAB   311808                    // uchar labels[2][2][8192]= 32768 B
#define OFF_CENT  344576                    // float cent[19][2048]    = 155648 B
#define OFF_DOTS  500224                    // float dots[57]
#define OFF_ROW   500452                    // float row[19]

typedef __attribute__((ext_vector_type(8))) short short8v;   // 8 bf16 (4 VGPRs)
typedef __attribute__((ext_vector_type(4))) float f32x4;     // MFMA C/D

__device__ inline short f32_to_bf16_bits(float x) {
  __hip_bfloat16 h = __float2bfloat16(x);
  return *reinterpret_cast<short*>(&h);
}

// ---------------------------------------------------------------------------
// Kernel 1: labels via align_corners bilinear downsample + argmax over C.
// 4 lanes per output pixel (5/5/5/4 channels each), shfl_xor argmax merge
// with first-max (lowest class index) tie-break. Replicates jnp.linspace
// f32 arithmetic and the reference's mul/add association exactly.
// ---------------------------------------------------------------------------
__global__ __launch_bounds__(256) void labels_kernel(
    const float* __restrict__ sm_s, const float* __restrict__ sm_t,
    unsigned char* __restrict__ labels, unsigned int* __restrict__ cnt) {
  __shared__ unsigned int lcnt[NC];
  int tid = threadIdx.x;
  if (tid < NC) lcnt[tid] = 0u;
  __syncthreads();

  int g = blockIdx.x * 256 + tid;          // 0..131071
  int pixid = g >> 2;                      // 0..32767
  int sub = g & 3;
  int dom = pixid >> 14;                   // block-uniform (64 pixels/block)
  int rem = pixid & 16383;
  int b   = rem >> 13;
  int pix = rem & (NPIX - 1);
  int oy  = pix >> 7;
  int ox  = pix & (FW - 1);

  const float* sm = dom ? sm_t : sm_s;

  const float step_y = 511.0f / 63.0f;     // f32, same as jnp.linspace delta
  const float step_x = 1023.0f / 127.0f;
  float fy = __fmul_rn((float)oy, step_y);
  float fx = __fmul_rn((float)ox, step_x);
  int y0 = (int)floorf(fy); int y1 = min(y0 + 1, SH - 1);
  int x0 = (int)floorf(fx); int x1 = min(x0 + 1, SW - 1);
  float wy = __fsub_rn(fy, (float)y0);
  float wx = __fsub_rn(fx, (float)x0);
  float omwy = __fsub_rn(1.0f, wy);
  float omwx = __fsub_rn(1.0f, wx);

  const float* base = sm + (size_t)b * (NC * SH * SW);
  float best = -1.0f; int bestc = 127;
  for (int c = sub; c < NC; c += 4) {
    const float* p = base + (size_t)c * (SH * SW);
    float v00 = p[y0 * SW + x0];
    float v01 = p[y0 * SW + x1];
    float v10 = p[y1 * SW + x0];
    float v11 = p[y1 * SW + x1];
    float r0  = __fadd_rn(__fmul_rn(v00, omwy), __fmul_rn(v10, wy));
    float r1  = __fadd_rn(__fmul_rn(v01, omwy), __fmul_rn(v11, wy));
    float val = __fadd_rn(__fmul_rn(r0, omwx), __fmul_rn(r1, wx));
    if (val > best) { best = val; bestc = c; }   // strict > == first-max in subset
  }
  // merge 4-lane group (lanes of one pixel are consecutive)
#pragma unroll
  for (int off = 1; off <= 2; off <<= 1) {
    float ov = __shfl_xor(best, off, 64);
    int   oc = __shfl_xor(bestc, off, 64);
    if (ov > best || (ov == best && oc < bestc)) { best = ov; bestc = oc; }
  }
  if (sub == 0) {
    labels[pixid] = (unsigned char)bestc;
    atomicAdd(&lcnt[bestc], 1u);
  }
  __syncthreads();
  if (tid < NC) atomicAdd(&cnt[dom * NC + tid], lcnt[tid]);  // block is dom-uniform
}

// ---------------------------------------------------------------------------
// Kernel 2 (hot): segment-sum as MFMA matmul.
//   S[f,c]  = sum_p feat[f,p]  * onehot[p,c]
//   Q[f,c]  = sum_p feat[f,p]^2* onehot[p,c]   (reduced over f -> Sq[c])
// A = feat (bf16-rn), loaded straight from global in A-fragment order
// (lane: row = l&15, k = 8*(l>>4)+j -> 8 consecutive f32 = 2 dwordx4).
// B = onehot built in-registers from labels (exact in bf16).
// Grid: 32 f-groups x 4 (d,b) planes x 16 K-splits = 2048 blocks, 4 waves:
// 8 blocks/CU -> 32 waves/CU (8/SIMD) to cover HBM latency with TLP
// (round-4 at 2 waves/SIMD was latency-bound at 0.9 TB/s).
// Epilogue: fire-and-forget f32 global atomics (16 colliders/address).
// ---------------------------------------------------------------------------
__global__ __launch_bounds__(256, 8) void segsum_kernel(
    const float* __restrict__ feat_s, const float* __restrict__ feat_t,
    const unsigned char* __restrict__ labels,
    float* __restrict__ sum, float* __restrict__ sq) {
  int tid = threadIdx.x;
  int wv = tid >> 6, l = tid & 63;
  int m16 = l & 15, grp = l >> 4;

  int bid = blockIdx.x;
  int fg    = bid & 31;                    // f-group (64 f each)
  int plane = (bid >> 5) & 3;              // (d,b)
  int ks    = bid >> 7;                    // K-split 0..15 (512 pix each)
  int d = plane >> 1, b = plane & 1;

  const float* feat = d ? feat_t : feat_s;
  int f_row = fg * 64 + wv * 16 + m16;     // A-fragment row for this lane
  const float* arow = feat + ((size_t)b * FDIM + f_row) * NPIX + ks * 512;
  const unsigned char* labp = labels + (d * 2 + b) * NPIX + ks * 512;

  f32x4 accS0 = {0.f,0.f,0.f,0.f}, accS1 = {0.f,0.f,0.f,0.f};
  f32x4 accQ0 = {0.f,0.f,0.f,0.f}, accQ1 = {0.f,0.f,0.f,0.f};

#pragma unroll 2
  for (int kt = 0; kt < 16; ++kt) {
    int k0 = kt * 32 + grp * 8;
    float4 v0 = *(const float4*)(arow + k0);
    float4 v1 = *(const float4*)(arow + k0 + 4);
    uint2 lw = *(const uint2*)(labp + k0);
    float vv0 = v0.x, vv1 = v0.y, vv2 = v0.z, vv3 = v0.w;
    float vv4 = v1.x, vv5 = v1.y, vv6 = v1.z, vv7 = v1.w;
    short8v a, a2, b0, b1;
#pragma unroll
    for (int j = 0; j < 8; ++j) {
      float x = (j==0)?vv0:(j==1)?vv1:(j==2)?vv2:(j==3)?vv3:(j==4)?vv4:(j==5)?vv5:(j==6)?vv6:vv7;
      a[j]  = f32_to_bf16_bits(x);
      a2[j] = f32_to_bf16_bits(x * x);
      unsigned lab = ((j < 4 ? lw.x : lw.y) >> ((j & 3) * 8)) & 0xFFu;
      b0[j] = (lab == (unsigned)m16)        ? (short)0x3F80 : (short)0;
      b1[j] = (lab == (unsigned)(m16 + 16)) ? (short)0x3F80 : (short)0;
    }
    accS0 = __builtin_amdgcn_mfma_f32_16x16x32_bf16(a,  b0, accS0, 0, 0, 0);
    accS1 = __builtin_amdgcn_mfma_f32_16x16x32_bf16(a,  b1, accS1, 0, 0, 0);
    accQ0 = __builtin_amdgcn_mfma_f32_16x16x32_bf16(a2, b0, accQ0, 0, 0, 0);
    accQ1 = __builtin_amdgcn_mfma_f32_16x16x32_bf16(a2, b1, accQ1, 0, 0, 0);
  }

  // C/D layout (verified): col = l&15 (= class), row = (l>>4)*4 + reg (= f).
  int c0 = l & 15;
  int fbw = fg * 64 + wv * 16 + (l >> 4) * 4;
  size_t sbase0 = ((size_t)d * NC + c0) * FDIM + fbw;
#pragma unroll
  for (int r = 0; r < 4; ++r) unsafeAtomicAdd(&sum[sbase0 + r], accS0[r]);
  if (c0 < 3) {
    size_t sbase1 = ((size_t)d * NC + 16 + c0) * FDIM + fbw;
#pragma unroll
    for (int r = 0; r < 4; ++r) unsafeAtomicAdd(&sum[sbase1 + r], accS1[r]);
  }
  // Sq: reduce Q over all 16 rows (4 regs + lanes l, l^16, l^32, l^48)
  float q0 = accQ0[0] + accQ0[1] + accQ0[2] + accQ0[3];
  float q1 = accQ1[0] + accQ1[1] + accQ1[2] + accQ1[3];
  q0 += __shfl_xor(q0, 16, 64); q0 += __shfl_xor(q0, 32, 64);
  q1 += __shfl_xor(q1, 16, 64); q1 += __shfl_xor(q1, 32, 64);
  if (l < 16) unsafeAtomicAdd(&sq[d * NC + l], q0);
  if (l < 3)  unsafeAtomicAdd(&sq[d * NC + 16 + l], q1);
}

// Block reduction helper (256 threads)
__device__ inline float block_reduce(float v, float* red, int tid) {
  red[tid] = v; __syncthreads();
  for (int s = 128; s > 0; s >>= 1) {
    if (tid < s) red[tid] += red[tid + s];
    __syncthreads();
  }
  float r = red[0];
  __syncthreads();
  return r;
}

// ---------------------------------------------------------------------------
// Kernel 3a: centroids[c][f] = (S_s + S_t)/max(cnt,1); also per-class
// dot_s = cent.S_s, dot_t = cent.S_t, cc = |cent|^2.
// ---------------------------------------------------------------------------
__global__ __launch_bounds__(256) void centroid_kernel(
    const float* __restrict__ sum, const unsigned int* __restrict__ cnt,
    float* __restrict__ cent, float* __restrict__ dots) {
  __shared__ float red[256];
  int c = blockIdx.x;
  int tid = threadIdx.x;
  float cs = (float)cnt[c];
  float ct = (float)cnt[NC + c];
  float denom = fmaxf(cs + ct, 1.0f);
  float ds = 0.f, dt = 0.f, cc = 0.f;
  for (int f = tid; f < FDIM; f += 256) {
    float ssv = sum[(size_t)c * FDIM + f];
    float stv = sum[(size_t)(NC + c) * FDIM + f];
    float cf = (ssv + stv) / denom;
    cent[(size_t)c * FDIM + f] = cf;
    ds += cf * ssv; dt += cf * stv; cc += cf * cf;
  }
  float rds = block_reduce(ds, red, tid);
  float rdt = block_reduce(dt, red, tid);
  float rcc = block_reduce(cc, red, tid);
  if (tid == 0) {
    dots[c] = rds;
    dots[NC + c] = rdt;
    dots[2 * NC + c] = rcc;
  }
}

// ---------------------------------------------------------------------------
// Kernel 3b: row[i] = sum_{j != i, seen i&j} sum_f (c_i - c_j)^2
// ---------------------------------------------------------------------------
__global__ __launch_bounds__(256) void pair_kernel(
    const float* __restrict__ cent, const unsigned int* __restrict__ cnt,
    float* __restrict__ row) {
  __shared__ float red[256];
  int i = blockIdx.x;
  int tid = threadIdx.x;
  bool seen_i = (cnt[i] + cnt[NC + i]) > 0u;
  float acc = 0.f;
  if (seen_i) {
    for (int j = 0; j < NC; ++j) {
      if (j == i) continue;
      if ((cnt[j] + cnt[NC + j]) == 0u) continue;
      for (int f = tid; f < FDIM; f += 256) {
        float dd = cent[(size_t)i * FDIM + f] - cent[(size_t)j * FDIM + f];
        acc += dd * dd;
      }
    }
  }
  float r = block_reduce(acc, red, tid);
  if (tid == 0) row[i] = r;
}

// ---------------------------------------------------------------------------
// Kernel 3c: assemble the 3 outputs (p == 2).
// ---------------------------------------------------------------------------
__global__ void final_kernel(
    const unsigned int* __restrict__ cnt, const float* __restrict__ sq,
    const float* __restrict__ dots, const float* __restrict__ row,
    float* __restrict__ out) {
  if (blockIdx.x != 0 || threadIdx.x != 0) return;
  const float fdim = (float)FDIM;
  int nseen = 0;
  for (int c = 0; c < NC; ++c)
    if (cnt[c] + cnt[NC + c] > 0u) nseen++;
  float nseenf = (float)nseen;

  float c_dist = 0.f, fs = 0.f, ft = 0.f;
  int nvs = 0, nvt = 0;
  for (int c = 0; c < NC; ++c) {
    float cs = (float)cnt[c];
    float ct = (float)cnt[NC + c];
    float cc = dots[2 * NC + c];
    if (cs > 0.f) {
      float ssq = sq[c] - 2.0f * dots[c] + cs * cc;
      ssq = fmaxf(ssq, 0.f);
      fs += sqrtf(ssq) / (cs * fdim);
      nvs++;
    }
    if (ct > 0.f) {
      float ssq = sq[NC + c] - 2.0f * dots[NC + c] + ct * cc;
      ssq = fmaxf(ssq, 0.f);
      ft += sqrtf(ssq) / (ct * fdim);
      nvt++;
    }
    if (cs + ct > 0.f) {
      c_dist += sqrtf(row[c]) / ((nseenf - 1.0f) * fdim);
    }
  }
  out[0] = c_dist / nseenf;
  out[1] = fs / (float)nvs;
  out[2] = ft / (float)nvt;
}

extern "C" void kernel_launch(void* const* d_in, const int* in_sizes, int n_in,
                              void* d_out, int out_size, void* d_ws, size_t ws_size,
                              hipStream_t stream) {
  const float* sfeat = (const float*)d_in[0];
  const float* ssm   = (const float*)d_in[1];
  const float* tfeat = (const float*)d_in[2];
  const float* tsm   = (const float*)d_in[3];
  float* out = (float*)d_out;

  char* ws = (char*)d_ws;
  float*         sq     = (float*)(ws + OFF_SQ);
  unsigned int*  cnt    = (unsigned int*)(ws + OFF_CNT);
  float*         sum    = (float*)(ws + OFF_SUM);
  unsigned char* labels = (unsigned char*)(ws + OFF_LAB);
  float*         cent   = (float*)(ws + OFF_CENT);
  float*         dots   = (float*)(ws + OFF_DOTS);
  float*         row    = (float*)(ws + OFF_ROW);

  // zero sq+cnt+sum (atomic accumulators; graph replays need re-zeroing)
  hipMemsetAsync(ws, 0, ZERO_BYTES, stream);

  labels_kernel  <<<512,  256, 0, stream>>>(ssm, tsm, labels, cnt);
  segsum_kernel  <<<2048, 256, 0, stream>>>(sfeat, tfeat, labels, sum, sq);
  centroid_kernel<<<NC,   256, 0, stream>>>(sum, cnt, cent, dots);
  pair_kernel    <<<NC,   256, 0, stream>>>(cent, cnt, row);
  final_kernel   <<<1,    64,  0, stream>>>(cnt, sq, dots, row, out);
}

// Round 6
// 142.310 us; speedup vs baseline: 1.7196x; 1.7196x over previous
//
#include <hip/hip_runtime.h>
#include <hip/hip_bf16.h>

// Problem constants
#define BB 2
#define FDIM 2048
#define FH 64
#define FW 128
#define NPIX (FH*FW)        // 8192 pixels per (dom,b)
#define NC 19
#define SH 512
#define SW 1024

#define KS 4                // pixel splits per (d,b) plane
#define PXS (NPIX/KS)       // 2048 pixels per block
#define NSTAGE (PXS/256)    // 8 stages of 256 px

// Workspace layout (bytes). psq+cnt+sum zeroed each launch (atomic accum).
#define OFF_PSQ   0                         // float psq[8][2][19]     = 1216 B (XCD partials)
#define OFF_CNT   1216                      // uint  cnt[2][19]        = 152 B
#define OFF_SUM   1408                      // float sum[2][19][2048]  = 311296 B
#define ZERO_BYTES 312704
#define OFF_LAB   312704                    // uchar labels[2][2][8192]= 32768 B
#define OFF_CENT  345472                    // float cent[19][2048]    = 155648 B
#define OFF_DOTS  501120                    // float dots[57]
#define OFF_ROW   501348                    // float row[19]

typedef __attribute__((ext_vector_type(8))) short short8v;   // 8 bf16 (4 VGPRs)
typedef __attribute__((ext_vector_type(4))) float f32x4;     // MFMA C/D

__device__ inline short f32_to_bf16_bits(float x) {
  __hip_bfloat16 h = __float2bfloat16(x);
  return *reinterpret_cast<short*>(&h);
}
__device__ inline float bf16_bits_to_f32(short s) {
  unsigned u = ((unsigned)s & 0xFFFFu) << 16;
  return __uint_as_float(u);
}

// ---------------------------------------------------------------------------
// Kernel 1: labels via align_corners bilinear downsample + argmax over C.
// 4 lanes per output pixel, shfl_xor argmax merge, first-max tie-break.
// Replicates jnp.linspace f32 arithmetic / mul-add association exactly.
// ---------------------------------------------------------------------------
__global__ __launch_bounds__(256) void labels_kernel(
    const float* __restrict__ sm_s, const float* __restrict__ sm_t,
    unsigned char* __restrict__ labels, unsigned int* __restrict__ cnt) {
  __shared__ unsigned int lcnt[NC];
  int tid = threadIdx.x;
  if (tid < NC) lcnt[tid] = 0u;
  __syncthreads();

  int g = blockIdx.x * 256 + tid;          // 0..131071
  int pixid = g >> 2;                      // 0..32767
  int sub = g & 3;
  int dom = pixid >> 14;                   // block-uniform
  int rem = pixid & 16383;
  int b   = rem >> 13;
  int pix = rem & (NPIX - 1);
  int oy  = pix >> 7;
  int ox  = pix & (FW - 1);

  const float* sm = dom ? sm_t : sm_s;

  const float step_y = 511.0f / 63.0f;
  const float step_x = 1023.0f / 127.0f;
  float fy = __fmul_rn((float)oy, step_y);
  float fx = __fmul_rn((float)ox, step_x);
  int y0 = (int)floorf(fy); int y1 = min(y0 + 1, SH - 1);
  int x0 = (int)floorf(fx); int x1 = min(x0 + 1, SW - 1);
  float wy = __fsub_rn(fy, (float)y0);
  float wx = __fsub_rn(fx, (float)x0);
  float omwy = __fsub_rn(1.0f, wy);
  float omwx = __fsub_rn(1.0f, wx);

  const float* base = sm + (size_t)b * (NC * SH * SW);
  float best = -1.0f; int bestc = 127;
  for (int c = sub; c < NC; c += 4) {
    const float* p = base + (size_t)c * (SH * SW);
    float v00 = p[y0 * SW + x0];
    float v01 = p[y0 * SW + x1];
    float v10 = p[y1 * SW + x0];
    float v11 = p[y1 * SW + x1];
    float r0  = __fadd_rn(__fmul_rn(v00, omwy), __fmul_rn(v10, wy));
    float r1  = __fadd_rn(__fmul_rn(v01, omwy), __fmul_rn(v11, wy));
    float val = __fadd_rn(__fmul_rn(r0, omwx), __fmul_rn(r1, wx));
    if (val > best) { best = val; bestc = c; }
  }
#pragma unroll
  for (int off = 1; off <= 2; off <<= 1) {
    float ov = __shfl_xor(best, off, 64);
    int   oc = __shfl_xor(bestc, off, 64);
    if (ov > best || (ov == best && oc < bestc)) { best = ov; bestc = oc; }
  }
  if (sub == 0) {
    labels[pixid] = (unsigned char)bestc;
    atomicAdd(&lcnt[bestc], 1u);
  }
  __syncthreads();
  if (tid < NC) atomicAdd(&cnt[dom * NC + tid], lcnt[tid]);
}

// ---------------------------------------------------------------------------
// Kernel 2 (hot): segment-sum as MFMA matmul, LDS-staged for STREAMING reads.
// Block = 16-row f-strip x (d,b) plane x 1/KS of pixels. Per stage (256 px):
//   - each wave loads 1KB CONTIGUOUS of one f-row (float4 x 64 lanes), 4 rounds
//   - converts f32->bf16 in-register, ds_writes into XOR-swizzled [16][256]
//     bf16 tile (double-buffered, 16KB); loads for stage s+1 issue before
//     compute of stage s (async-split)
//   - each wave computes 2 MFMA K-steps: A-frag = 1 ds_read_b128 (swizzled),
//     A2 = square-in-register, B = onehot from LDS-staged labels
// blockIdx encoding keeps all atomic colliders of a sum-address on ONE XCD
// (bid%8 == strip%8) -> L2-local atomics, no cross-XCD line bouncing.
// Sq goes to per-XCD partials psq[8][2][19], folded in final_kernel.
// ---------------------------------------------------------------------------
__global__ __launch_bounds__(256, 6) void segsum_kernel(
    const float* __restrict__ feat_s, const float* __restrict__ feat_t,
    const unsigned char* __restrict__ labels,
    float* __restrict__ sum, float* __restrict__ psq) {
  __shared__ unsigned short Abuf[2][16][256];   // bf16 bits, swizzled; 16KB
  __shared__ unsigned char  Lbuf[2][256];       // label window

  int tid = threadIdx.x;
  int wv = tid >> 6, l = tid & 63;
  int m16 = l & 15, grp = l >> 4;

  // bid = (d*128 + strip) + 256*(ks*2 + b): colliders (all b,ks of same
  // (d,strip)) share bid%8 = strip%8 -> same XCD.
  int low = blockIdx.x & 255;
  int hi  = blockIdx.x >> 8;                 // 0..7
  int d = low >> 7, strip = low & 127;
  int b = hi & 1, ks = hi >> 1;

  const float* feat = d ? feat_t : feat_s;
  const float* fbase = feat + ((size_t)(b * FDIM + strip * 16)) * NPIX + ks * PXS;
  const unsigned char* labp = labels + (d * 2 + b) * NPIX + ks * PXS;

  // ---- prologue: stage 0 ----
  float4 ld[4];
#pragma unroll
  for (int r = 0; r < 4; ++r)
    ld[r] = *(const float4*)(fbase + (size_t)(r * 4 + wv) * NPIX + l * 4);
  uint2 lwstage = make_uint2(0u, 0u);
  if (tid < 32) lwstage = *(const uint2*)(labp + tid * 8);

#pragma unroll
  for (int r = 0; r < 4; ++r) {
    int row = r * 4 + wv;
    unsigned u0 = ((unsigned)(unsigned short)f32_to_bf16_bits(ld[r].x)) |
                  (((unsigned)(unsigned short)f32_to_bf16_bits(ld[r].y)) << 16);
    unsigned u1 = ((unsigned)(unsigned short)f32_to_bf16_bits(ld[r].z)) |
                  (((unsigned)(unsigned short)f32_to_bf16_bits(ld[r].w)) << 16);
    int wbyte = (l * 8) ^ ((row & 7) << 4);
    *(uint2*)((char*)&Abuf[0][row][0] + wbyte) = make_uint2(u0, u1);
  }
  if (tid < 32) *(uint2*)&Lbuf[0][tid * 8] = lwstage;
  __syncthreads();

  f32x4 accS0 = {0.f,0.f,0.f,0.f}, accS1 = {0.f,0.f,0.f,0.f};
  f32x4 accQ0 = {0.f,0.f,0.f,0.f}, accQ1 = {0.f,0.f,0.f,0.f};

  for (int s = 0; s < NSTAGE; ++s) {
    int cur = s & 1;
    // issue next stage's global loads (latency hides under compute)
    if (s < NSTAGE - 1) {
#pragma unroll
      for (int r = 0; r < 4; ++r)
        ld[r] = *(const float4*)(fbase + (size_t)(r * 4 + wv) * NPIX +
                                 (s + 1) * 256 + l * 4);
      if (tid < 32) lwstage = *(const uint2*)(labp + (s + 1) * 256 + tid * 8);
    }
    // compute: wave wv handles kt = wv*2 + {0,1} of this 256-px window
#pragma unroll
    for (int t = 0; t < 2; ++t) {
      int kt = wv * 2 + t;
      int k0 = kt * 32 + grp * 8;
      int rbyte = (k0 * 2) ^ ((m16 & 7) << 4);
      short8v a = *(const short8v*)((const char*)&Abuf[cur][m16][0] + rbyte);
      short8v a2;
#pragma unroll
      for (int j = 0; j < 8; ++j) {
        float x = bf16_bits_to_f32(a[j]);
        a2[j] = f32_to_bf16_bits(x * x);
      }
      uint2 lw = *(const uint2*)&Lbuf[cur][k0];
      short8v b0, b1;
#pragma unroll
      for (int j = 0; j < 8; ++j) {
        unsigned lab = ((j < 4 ? lw.x : lw.y) >> ((j & 3) * 8)) & 0xFFu;
        b0[j] = (lab == (unsigned)m16)        ? (short)0x3F80 : (short)0;
        b1[j] = (lab == (unsigned)(m16 + 16)) ? (short)0x3F80 : (short)0;
      }
      accS0 = __builtin_amdgcn_mfma_f32_16x16x32_bf16(a,  b0, accS0, 0, 0, 0);
      accS1 = __builtin_amdgcn_mfma_f32_16x16x32_bf16(a,  b1, accS1, 0, 0, 0);
      accQ0 = __builtin_amdgcn_mfma_f32_16x16x32_bf16(a2, b0, accQ0, 0, 0, 0);
      accQ1 = __builtin_amdgcn_mfma_f32_16x16x32_bf16(a2, b1, accQ1, 0, 0, 0);
    }
    __syncthreads();
    if (s < NSTAGE - 1) {
#pragma unroll
      for (int r = 0; r < 4; ++r) {
        int row = r * 4 + wv;
        unsigned u0 = ((unsigned)(unsigned short)f32_to_bf16_bits(ld[r].x)) |
                      (((unsigned)(unsigned short)f32_to_bf16_bits(ld[r].y)) << 16);
        unsigned u1 = ((unsigned)(unsigned short)f32_to_bf16_bits(ld[r].z)) |
                      (((unsigned)(unsigned short)f32_to_bf16_bits(ld[r].w)) << 16);
        int wbyte = (l * 8) ^ ((row & 7) << 4);
        *(uint2*)((char*)&Abuf[cur ^ 1][row][0] + wbyte) = make_uint2(u0, u1);
      }
      if (tid < 32) *(uint2*)&Lbuf[cur ^ 1][tid * 8] = lwstage;
      __syncthreads();
    }
  }

  // ---- epilogue: merge 4 waves via LDS (alias Abuf), then XCD-local atomics
  float* Sred = (float*)&Abuf[0][0][0];      // [4][19][16] = 4864 B
  float* Qred = Sred + 4 * 19 * 16;          // [4][19]

  int c0 = l & 15, frb = (l >> 4) * 4;       // C/D: col=class, row=(l>>4)*4+reg
  *(f32x4*)&Sred[(wv * 19 + c0) * 16 + frb] = accS0;
  if (c0 < 3) *(f32x4*)&Sred[(wv * 19 + 16 + c0) * 16 + frb] = accS1;

  float q0 = accQ0[0] + accQ0[1] + accQ0[2] + accQ0[3];
  float q1 = accQ1[0] + accQ1[1] + accQ1[2] + accQ1[3];
  q0 += __shfl_xor(q0, 16, 64); q0 += __shfl_xor(q0, 32, 64);
  q1 += __shfl_xor(q1, 16, 64); q1 += __shfl_xor(q1, 32, 64);
  if (l < 16) Qred[wv * 19 + l] = q0;
  if (l < 3)  Qred[wv * 19 + 16 + l] = q1;
  __syncthreads();

  for (int t = tid; t < NC * 16; t += 256) {
    int c = t >> 4, fr = t & 15;
    float sv = Sred[(0 * 19 + c) * 16 + fr] + Sred[(1 * 19 + c) * 16 + fr] +
               Sred[(2 * 19 + c) * 16 + fr] + Sred[(3 * 19 + c) * 16 + fr];
    unsafeAtomicAdd(&sum[((size_t)d * NC + c) * FDIM + strip * 16 + fr], sv);
  }
  if (tid < NC) {
    float qv = Qred[tid] + Qred[19 + tid] + Qred[38 + tid] + Qred[57 + tid];
    unsafeAtomicAdd(&psq[(blockIdx.x & 7) * (2 * NC) + d * NC + tid], qv);
  }
}

// Block reduction helper (256 threads)
__device__ inline float block_reduce(float v, float* red, int tid) {
  red[tid] = v; __syncthreads();
  for (int s = 128; s > 0; s >>= 1) {
    if (tid < s) red[tid] += red[tid + s];
    __syncthreads();
  }
  float r = red[0];
  __syncthreads();
  return r;
}

// ---------------------------------------------------------------------------
// Kernel 3a: centroids + per-class dots.
// ---------------------------------------------------------------------------
__global__ __launch_bounds__(256) void centroid_kernel(
    const float* __restrict__ sum, const unsigned int* __restrict__ cnt,
    float* __restrict__ cent, float* __restrict__ dots) {
  __shared__ float red[256];
  int c = blockIdx.x;
  int tid = threadIdx.x;
  float cs = (float)cnt[c];
  float ct = (float)cnt[NC + c];
  float denom = fmaxf(cs + ct, 1.0f);
  float ds = 0.f, dt = 0.f, cc = 0.f;
  for (int f = tid; f < FDIM; f += 256) {
    float ssv = sum[(size_t)c * FDIM + f];
    float stv = sum[(size_t)(NC + c) * FDIM + f];
    float cf = (ssv + stv) / denom;
    cent[(size_t)c * FDIM + f] = cf;
    ds += cf * ssv; dt += cf * stv; cc += cf * cf;
  }
  float rds = block_reduce(ds, red, tid);
  float rdt = block_reduce(dt, red, tid);
  float rcc = block_reduce(cc, red, tid);
  if (tid == 0) {
    dots[c] = rds;
    dots[NC + c] = rdt;
    dots[2 * NC + c] = rcc;
  }
}

// ---------------------------------------------------------------------------
// Kernel 3b: row[i] = sum_{j != i, seen i&j} sum_f (c_i - c_j)^2
// ---------------------------------------------------------------------------
__global__ __launch_bounds__(256) void pair_kernel(
    const float* __restrict__ cent, const unsigned int* __restrict__ cnt,
    float* __restrict__ row) {
  __shared__ float red[256];
  int i = blockIdx.x;
  int tid = threadIdx.x;
  bool seen_i = (cnt[i] + cnt[NC + i]) > 0u;
  float acc = 0.f;
  if (seen_i) {
    for (int j = 0; j < NC; ++j) {
      if (j == i) continue;
      if ((cnt[j] + cnt[NC + j]) == 0u) continue;
      for (int f = tid; f < FDIM; f += 256) {
        float dd = cent[(size_t)i * FDIM + f] - cent[(size_t)j * FDIM + f];
        acc += dd * dd;
      }
    }
  }
  float r = block_reduce(acc, red, tid);
  if (tid == 0) row[i] = r;
}

// ---------------------------------------------------------------------------
// Kernel 3c: fold psq partials, assemble the 3 outputs (p == 2).
// ---------------------------------------------------------------------------
__global__ void final_kernel(
    const unsigned int* __restrict__ cnt, const float* __restrict__ psq,
    const float* __restrict__ dots, const float* __restrict__ row,
    float* __restrict__ out) {
  if (blockIdx.x != 0 || threadIdx.x != 0) return;
  const float fdim = (float)FDIM;
  float sqv[2 * NC];
  for (int c = 0; c < 2 * NC; ++c) {
    float q = 0.f;
    for (int x = 0; x < 8; ++x) q += psq[x * (2 * NC) + c];
    sqv[c] = q;
  }
  int nseen = 0;
  for (int c = 0; c < NC; ++c)
    if (cnt[c] + cnt[NC + c] > 0u) nseen++;
  float nseenf = (float)nseen;

  float c_dist = 0.f, fs = 0.f, ft = 0.f;
  int nvs = 0, nvt = 0;
  for (int c = 0; c < NC; ++c) {
    float cs = (float)cnt[c];
    float ct = (float)cnt[NC + c];
    float cc = dots[2 * NC + c];
    if (cs > 0.f) {
      float ssq = sqv[c] - 2.0f * dots[c] + cs * cc;
      ssq = fmaxf(ssq, 0.f);
      fs += sqrtf(ssq) / (cs * fdim);
      nvs++;
    }
    if (ct > 0.f) {
      float ssq = sqv[NC + c] - 2.0f * dots[NC + c] + ct * cc;
      ssq = fmaxf(ssq, 0.f);
      ft += sqrtf(ssq) / (ct * fdim);
      nvt++;
    }
    if (cs + ct > 0.f) {
      c_dist += sqrtf(row[c]) / ((nseenf - 1.0f) * fdim);
    }
  }
  out[0] = c_dist / nseenf;
  out[1] = fs / (float)nvs;
  out[2] = ft / (float)nvt;
}

extern "C" void kernel_launch(void* const* d_in, const int* in_sizes, int n_in,
                              void* d_out, int out_size, void* d_ws, size_t ws_size,
                              hipStream_t stream) {
  const float* sfeat = (const float*)d_in[0];
  const float* ssm   = (const float*)d_in[1];
  const float* tfeat = (const float*)d_in[2];
  const float* tsm   = (const float*)d_in[3];
  float* out = (float*)d_out;

  char* ws = (char*)d_ws;
  float*         psq    = (float*)(ws + OFF_PSQ);
  unsigned int*  cnt    = (unsigned int*)(ws + OFF_CNT);
  float*         sum    = (float*)(ws + OFF_SUM);
  unsigned char* labels = (unsigned char*)(ws + OFF_LAB);
  float*         cent   = (float*)(ws + OFF_CENT);
  float*         dots   = (float*)(ws + OFF_DOTS);
  float*         row    = (float*)(ws + OFF_ROW);

  // zero psq+cnt+sum (atomic accumulators; graph replays need re-zeroing)
  hipMemsetAsync(ws, 0, ZERO_BYTES, stream);

  labels_kernel  <<<512,  256, 0, stream>>>(ssm, tsm, labels, cnt);
  segsum_kernel  <<<2048, 256, 0, stream>>>(sfeat, tfeat, labels, sum, psq);
  centroid_kernel<<<NC,   256, 0, stream>>>(sum, cnt, cent, dots);
  pair_kernel    <<<NC,   256, 0, stream>>>(cent, cnt, row);
  final_kernel   <<<1,    64,  0, stream>>>(cnt, psq, dots, row, out);
}

// Round 7
// 120.543 us; speedup vs baseline: 2.0301x; 1.1806x over previous
//
#include <hip/hip_runtime.h>
#include <hip/hip_bf16.h>

// Problem constants
#define BB 2
#define FDIM 2048
#define FH 64
#define FW 128
#define NPIX (FH*FW)        // 8192 pixels per (dom,b)
#define NC 19
#define SH 512
#define SW 1024

#define KS 4                // pixel splits per (d,b) plane
#define PXS (NPIX/KS)       // 2048 pixels per block
#define NSTAGE (PXS/256)    // 8 stages of 256 px

// Workspace layout (bytes). psq+cnt+sum zeroed each launch (atomic accum).
#define OFF_PSQ   0                         // float psq[8][2][19]     = 1216 B (XCD partials)
#define OFF_CNT   1216                      // uint  cnt[2][19]        = 152 B
#define OFF_SUM   1408                      // float sum[2][19][2048]  = 311296 B
#define ZERO_BYTES 312704
#define OFF_LAB   312704                    // uchar labels[2][2][8192]= 32768 B
#define OFF_CENT  345472                    // float cent[19][2048]    = 155648 B
#define OFF_DOTS  501120                    // float dots[57]
#define OFF_ROW   501348                    // float row[19]

typedef __attribute__((ext_vector_type(8))) short short8v;   // 8 bf16 (4 VGPRs)
typedef __attribute__((ext_vector_type(4))) float f32x4;     // MFMA C/D

__device__ inline short f32_to_bf16_bits(float x) {
  __hip_bfloat16 h = __float2bfloat16(x);
  return *reinterpret_cast<short*>(&h);
}
__device__ inline float bf16_bits_to_f32(short s) {
  unsigned u = ((unsigned)s & 0xFFFFu) << 16;
  return __uint_as_float(u);
}

// ---------------------------------------------------------------------------
// Kernel 1: labels via align_corners bilinear downsample + argmax over C.
// 4 lanes per output pixel, shfl_xor argmax merge, first-max tie-break.
// Replicates jnp.linspace f32 arithmetic / mul-add association exactly.
// ---------------------------------------------------------------------------
__global__ __launch_bounds__(256) void labels_kernel(
    const float* __restrict__ sm_s, const float* __restrict__ sm_t,
    unsigned char* __restrict__ labels, unsigned int* __restrict__ cnt) {
  __shared__ unsigned int lcnt[NC];
  int tid = threadIdx.x;
  if (tid < NC) lcnt[tid] = 0u;
  __syncthreads();

  int g = blockIdx.x * 256 + tid;          // 0..131071
  int pixid = g >> 2;                      // 0..32767
  int sub = g & 3;
  int dom = pixid >> 14;                   // block-uniform
  int rem = pixid & 16383;
  int b   = rem >> 13;
  int pix = rem & (NPIX - 1);
  int oy  = pix >> 7;
  int ox  = pix & (FW - 1);

  const float* sm = dom ? sm_t : sm_s;

  const float step_y = 511.0f / 63.0f;
  const float step_x = 1023.0f / 127.0f;
  float fy = __fmul_rn((float)oy, step_y);
  float fx = __fmul_rn((float)ox, step_x);
  int y0 = (int)floorf(fy); int y1 = min(y0 + 1, SH - 1);
  int x0 = (int)floorf(fx); int x1 = min(x0 + 1, SW - 1);
  float wy = __fsub_rn(fy, (float)y0);
  float wx = __fsub_rn(fx, (float)x0);
  float omwy = __fsub_rn(1.0f, wy);
  float omwx = __fsub_rn(1.0f, wx);

  const float* base = sm + (size_t)b * (NC * SH * SW);
  float best = -1.0f; int bestc = 127;
  for (int c = sub; c < NC; c += 4) {
    const float* p = base + (size_t)c * (SH * SW);
    float v00 = p[y0 * SW + x0];
    float v01 = p[y0 * SW + x1];
    float v10 = p[y1 * SW + x0];
    float v11 = p[y1 * SW + x1];
    float r0  = __fadd_rn(__fmul_rn(v00, omwy), __fmul_rn(v10, wy));
    float r1  = __fadd_rn(__fmul_rn(v01, omwy), __fmul_rn(v11, wy));
    float val = __fadd_rn(__fmul_rn(r0, omwx), __fmul_rn(r1, wx));
    if (val > best) { best = val; bestc = c; }
  }
#pragma unroll
  for (int off = 1; off <= 2; off <<= 1) {
    float ov = __shfl_xor(best, off, 64);
    int   oc = __shfl_xor(bestc, off, 64);
    if (ov > best || (ov == best && oc < bestc)) { best = ov; bestc = oc; }
  }
  if (sub == 0) {
    labels[pixid] = (unsigned char)bestc;
    atomicAdd(&lcnt[bestc], 1u);
  }
  __syncthreads();
  if (tid < NC) atomicAdd(&cnt[dom * NC + tid], lcnt[tid]);
}

// ---------------------------------------------------------------------------
// Kernel 2 (hot): segment-sum as MFMA matmul, LDS-staged for STREAMING reads.
// Block = 16-row f-strip x (d,b) plane x 1/KS of pixels. Per stage (256 px):
//   - each wave loads 1KB CONTIGUOUS of one f-row (float4 x 64 lanes), 4 rounds
//   - converts f32->bf16 in-register, ds_writes into XOR-swizzled [16][256]
//     bf16 tile (double-buffered, 16KB); loads for stage s+1 issue before
//     compute of stage s (async-split)
//   - each wave computes 2 MFMA K-steps: A-frag = 1 ds_read_b128 (swizzled),
//     A2 = square-in-register, B = onehot from LDS-staged labels
// blockIdx encoding keeps all atomic colliders of a sum-address on ONE XCD
// (bid%8 == strip%8) -> L2-local atomics, no cross-XCD line bouncing.
// Sq goes to per-XCD partials psq[8][2][19], folded in final_kernel.
// ---------------------------------------------------------------------------
__global__ __launch_bounds__(256, 6) void segsum_kernel(
    const float* __restrict__ feat_s, const float* __restrict__ feat_t,
    const unsigned char* __restrict__ labels,
    float* __restrict__ sum, float* __restrict__ psq) {
  __shared__ unsigned short Abuf[2][16][256];   // bf16 bits, swizzled; 16KB
  __shared__ unsigned char  Lbuf[2][256];       // label window

  int tid = threadIdx.x;
  int wv = tid >> 6, l = tid & 63;
  int m16 = l & 15, grp = l >> 4;

  // bid = (d*128 + strip) + 256*(ks*2 + b): colliders (all b,ks of same
  // (d,strip)) share bid%8 = strip%8 -> same XCD.
  int low = blockIdx.x & 255;
  int hi  = blockIdx.x >> 8;                 // 0..7
  int d = low >> 7, strip = low & 127;
  int b = hi & 1, ks = hi >> 1;

  const float* feat = d ? feat_t : feat_s;
  const float* fbase = feat + ((size_t)(b * FDIM + strip * 16)) * NPIX + ks * PXS;
  const unsigned char* labp = labels + (d * 2 + b) * NPIX + ks * PXS;

  // ---- prologue: stage 0 ----
  float4 ld[4];
#pragma unroll
  for (int r = 0; r < 4; ++r)
    ld[r] = *(const float4*)(fbase + (size_t)(r * 4 + wv) * NPIX + l * 4);
  uint2 lwstage = make_uint2(0u, 0u);
  if (tid < 32) lwstage = *(const uint2*)(labp + tid * 8);

#pragma unroll
  for (int r = 0; r < 4; ++r) {
    int row = r * 4 + wv;
    unsigned u0 = ((unsigned)(unsigned short)f32_to_bf16_bits(ld[r].x)) |
                  (((unsigned)(unsigned short)f32_to_bf16_bits(ld[r].y)) << 16);
    unsigned u1 = ((unsigned)(unsigned short)f32_to_bf16_bits(ld[r].z)) |
                  (((unsigned)(unsigned short)f32_to_bf16_bits(ld[r].w)) << 16);
    int wbyte = (l * 8) ^ ((row & 7) << 4);
    *(uint2*)((char*)&Abuf[0][row][0] + wbyte) = make_uint2(u0, u1);
  }
  if (tid < 32) *(uint2*)&Lbuf[0][tid * 8] = lwstage;
  __syncthreads();

  f32x4 accS0 = {0.f,0.f,0.f,0.f}, accS1 = {0.f,0.f,0.f,0.f};
  f32x4 accQ0 = {0.f,0.f,0.f,0.f}, accQ1 = {0.f,0.f,0.f,0.f};

  for (int s = 0; s < NSTAGE; ++s) {
    int cur = s & 1;
    // issue next stage's global loads (latency hides under compute)
    if (s < NSTAGE - 1) {
#pragma unroll
      for (int r = 0; r < 4; ++r)
        ld[r] = *(const float4*)(fbase + (size_t)(r * 4 + wv) * NPIX +
                                 (s + 1) * 256 + l * 4);
      if (tid < 32) lwstage = *(const uint2*)(labp + (s + 1) * 256 + tid * 8);
    }
    // compute: wave wv handles kt = wv*2 + {0,1} of this 256-px window
#pragma unroll
    for (int t = 0; t < 2; ++t) {
      int kt = wv * 2 + t;
      int k0 = kt * 32 + grp * 8;
      int rbyte = (k0 * 2) ^ ((m16 & 7) << 4);
      short8v a = *(const short8v*)((const char*)&Abuf[cur][m16][0] + rbyte);
      short8v a2;
#pragma unroll
      for (int j = 0; j < 8; ++j) {
        float x = bf16_bits_to_f32(a[j]);
        a2[j] = f32_to_bf16_bits(x * x);
      }
      uint2 lw = *(const uint2*)&Lbuf[cur][k0];
      short8v b0, b1;
#pragma unroll
      for (int j = 0; j < 8; ++j) {
        unsigned lab = ((j < 4 ? lw.x : lw.y) >> ((j & 3) * 8)) & 0xFFu;
        b0[j] = (lab == (unsigned)m16)        ? (short)0x3F80 : (short)0;
        b1[j] = (lab == (unsigned)(m16 + 16)) ? (short)0x3F80 : (short)0;
      }
      accS0 = __builtin_amdgcn_mfma_f32_16x16x32_bf16(a,  b0, accS0, 0, 0, 0);
      accS1 = __builtin_amdgcn_mfma_f32_16x16x32_bf16(a,  b1, accS1, 0, 0, 0);
      accQ0 = __builtin_amdgcn_mfma_f32_16x16x32_bf16(a2, b0, accQ0, 0, 0, 0);
      accQ1 = __builtin_amdgcn_mfma_f32_16x16x32_bf16(a2, b1, accQ1, 0, 0, 0);
    }
    __syncthreads();
    if (s < NSTAGE - 1) {
#pragma unroll
      for (int r = 0; r < 4; ++r) {
        int row = r * 4 + wv;
        unsigned u0 = ((unsigned)(unsigned short)f32_to_bf16_bits(ld[r].x)) |
                      (((unsigned)(unsigned short)f32_to_bf16_bits(ld[r].y)) << 16);
        unsigned u1 = ((unsigned)(unsigned short)f32_to_bf16_bits(ld[r].z)) |
                      (((unsigned)(unsigned short)f32_to_bf16_bits(ld[r].w)) << 16);
        int wbyte = (l * 8) ^ ((row & 7) << 4);
        *(uint2*)((char*)&Abuf[cur ^ 1][row][0] + wbyte) = make_uint2(u0, u1);
      }
      if (tid < 32) *(uint2*)&Lbuf[cur ^ 1][tid * 8] = lwstage;
      __syncthreads();
    }
  }

  // ---- epilogue: merge 4 waves via LDS (alias Abuf), then XCD-local atomics
  float* Sred = (float*)&Abuf[0][0][0];      // [4][19][16] = 4864 B
  float* Qred = Sred + 4 * 19 * 16;          // [4][19]

  int c0 = l & 15, frb = (l >> 4) * 4;       // C/D: col=class, row=(l>>4)*4+reg
  *(f32x4*)&Sred[(wv * 19 + c0) * 16 + frb] = accS0;
  if (c0 < 3) *(f32x4*)&Sred[(wv * 19 + 16 + c0) * 16 + frb] = accS1;

  float q0 = accQ0[0] + accQ0[1] + accQ0[2] + accQ0[3];
  float q1 = accQ1[0] + accQ1[1] + accQ1[2] + accQ1[3];
  q0 += __shfl_xor(q0, 16, 64); q0 += __shfl_xor(q0, 32, 64);
  q1 += __shfl_xor(q1, 16, 64); q1 += __shfl_xor(q1, 32, 64);
  if (l < 16) Qred[wv * 19 + l] = q0;
  if (l < 3)  Qred[wv * 19 + 16 + l] = q1;
  __syncthreads();

  for (int t = tid; t < NC * 16; t += 256) {
    int c = t >> 4, fr = t & 15;
    float sv = Sred[(0 * 19 + c) * 16 + fr] + Sred[(1 * 19 + c) * 16 + fr] +
               Sred[(2 * 19 + c) * 16 + fr] + Sred[(3 * 19 + c) * 16 + fr];
    unsafeAtomicAdd(&sum[((size_t)d * NC + c) * FDIM + strip * 16 + fr], sv);
  }
  if (tid < NC) {
    float qv = Qred[tid] + Qred[19 + tid] + Qred[38 + tid] + Qred[57 + tid];
    unsafeAtomicAdd(&psq[(blockIdx.x & 7) * (2 * NC) + d * NC + tid], qv);
  }
}

// Block reduction helper (256 threads)
__device__ inline float block_reduce(float v, float* red, int tid) {
  red[tid] = v; __syncthreads();
  for (int s = 128; s > 0; s >>= 1) {
    if (tid < s) red[tid] += red[tid + s];
    __syncthreads();
  }
  float r = red[0];
  __syncthreads();
  return r;
}

// ---------------------------------------------------------------------------
// Kernel 3a: centroids + per-class dots.
// ---------------------------------------------------------------------------
__global__ __launch_bounds__(256) void centroid_kernel(
    const float* __restrict__ sum, const unsigned int* __restrict__ cnt,
    float* __restrict__ cent, float* __restrict__ dots) {
  __shared__ float red[256];
  int c = blockIdx.x;
  int tid = threadIdx.x;
  float cs = (float)cnt[c];
  float ct = (float)cnt[NC + c];
  float denom = fmaxf(cs + ct, 1.0f);
  float ds = 0.f, dt = 0.f, cc = 0.f;
  for (int f = tid; f < FDIM; f += 256) {
    float ssv = sum[(size_t)c * FDIM + f];
    float stv = sum[(size_t)(NC + c) * FDIM + f];
    float cf = (ssv + stv) / denom;
    cent[(size_t)c * FDIM + f] = cf;
    ds += cf * ssv; dt += cf * stv; cc += cf * cf;
  }
  float rds = block_reduce(ds, red, tid);
  float rdt = block_reduce(dt, red, tid);
  float rcc = block_reduce(cc, red, tid);
  if (tid == 0) {
    dots[c] = rds;
    dots[NC + c] = rdt;
    dots[2 * NC + c] = rcc;
  }
}

// ---------------------------------------------------------------------------
// Kernel 3b: row[i] = sum_{j != i, seen i&j} sum_f (c_i - c_j)^2
// ---------------------------------------------------------------------------
__global__ __launch_bounds__(256) void pair_kernel(
    const float* __restrict__ cent, const unsigned int* __restrict__ cnt,
    float* __restrict__ row) {
  __shared__ float red[256];
  int i = blockIdx.x;
  int tid = threadIdx.x;
  bool seen_i = (cnt[i] + cnt[NC + i]) > 0u;
  float acc = 0.f;
  if (seen_i) {
    for (int j = 0; j < NC; ++j) {
      if (j == i) continue;
      if ((cnt[j] + cnt[NC + j]) == 0u) continue;
      for (int f = tid; f < FDIM; f += 256) {
        float dd = cent[(size_t)i * FDIM + f] - cent[(size_t)j * FDIM + f];
        acc += dd * dd;
      }
    }
  }
  float r = block_reduce(acc, red, tid);
  if (tid == 0) row[i] = r;
}

// ---------------------------------------------------------------------------
// Kernel 3c: fold psq partials, assemble the 3 outputs (p == 2).
// ONE WAVE, parallel loads: lane c handles class c (c < 19); ballot/popc for
// counts, shfl_down tree for sums. (The old 1-lane version serially issued
// ~420 cross-XCD HBM loads -> 149 us.)
// ---------------------------------------------------------------------------
__global__ void final_kernel(
    const unsigned int* __restrict__ cnt, const float* __restrict__ psq,
    const float* __restrict__ dots, const float* __restrict__ row,
    float* __restrict__ out) {
  int l = threadIdx.x;                      // one wave of 64
  const float fdim = (float)FDIM;
  bool isC = l < NC;
  int c = isC ? l : 0;

  float cs = 0.f, ct = 0.f, qs = 0.f, qt = 0.f;
  float d_s = 0.f, d_t = 0.f, cc = 0.f, rw = 0.f;
  if (isC) {
    cs = (float)cnt[c]; ct = (float)cnt[NC + c];
#pragma unroll
    for (int x = 0; x < 8; ++x) {           // 16 independent loads, all in flight
      qs += psq[x * (2 * NC) + c];
      qt += psq[x * (2 * NC) + NC + c];
    }
    d_s = dots[c]; d_t = dots[NC + c]; cc = dots[2 * NC + c];
    rw = row[c];
  }
  bool seen = isC && (cs + ct > 0.f);
  float nseenf = (float)__popcll(__ballot(seen));
  float nvs    = (float)__popcll(__ballot(isC && cs > 0.f));
  float nvt    = (float)__popcll(__ballot(isC && ct > 0.f));

  float fs = 0.f, ft = 0.f, cd = 0.f;
  if (isC && cs > 0.f) {
    float ssq = fmaxf(qs - 2.0f * d_s + cs * cc, 0.f);
    fs = sqrtf(ssq) / (cs * fdim);
  }
  if (isC && ct > 0.f) {
    float ssq = fmaxf(qt - 2.0f * d_t + ct * cc, 0.f);
    ft = sqrtf(ssq) / (ct * fdim);
  }
  if (seen) cd = sqrtf(rw) / ((nseenf - 1.0f) * fdim);

#pragma unroll
  for (int off = 32; off > 0; off >>= 1) {
    fs += __shfl_down(fs, off, 64);
    ft += __shfl_down(ft, off, 64);
    cd += __shfl_down(cd, off, 64);
  }
  if (l == 0) {
    out[0] = cd / nseenf;
    out[1] = fs / nvs;
    out[2] = ft / nvt;
  }
}

extern "C" void kernel_launch(void* const* d_in, const int* in_sizes, int n_in,
                              void* d_out, int out_size, void* d_ws, size_t ws_size,
                              hipStream_t stream) {
  const float* sfeat = (const float*)d_in[0];
  const float* ssm   = (const float*)d_in[1];
  const float* tfeat = (const float*)d_in[2];
  const float* tsm   = (const float*)d_in[3];
  float* out = (float*)d_out;

  char* ws = (char*)d_ws;
  float*         psq    = (float*)(ws + OFF_PSQ);
  unsigned int*  cnt    = (unsigned int*)(ws + OFF_CNT);
  float*         sum    = (float*)(ws + OFF_SUM);
  unsigned char* labels = (unsigned char*)(ws + OFF_LAB);
  float*         cent   = (float*)(ws + OFF_CENT);
  float*         dots   = (float*)(ws + OFF_DOTS);
  float*         row    = (float*)(ws + OFF_ROW);

  // zero psq+cnt+sum (atomic accumulators; graph replays need re-zeroing)
  hipMemsetAsync(ws, 0, ZERO_BYTES, stream);

  labels_kernel  <<<512,  256, 0, stream>>>(ssm, tsm, labels, cnt);
  segsum_kernel  <<<2048, 256, 0, stream>>>(sfeat, tfeat, labels, sum, psq);
  centroid_kernel<<<NC,   256, 0, stream>>>(sum, cnt, cent, dots);
  pair_kernel    <<<NC,   256, 0, stream>>>(cent, cnt, row);
  final_kernel   <<<1,    64,  0, stream>>>(cnt, psq, dots, row, out);
}

// Round 8
// 111.595 us; speedup vs baseline: 2.1929x; 1.0802x over previous
//
#include <hip/hip_runtime.h>
#include <hip/hip_bf16.h>

// Problem constants
#define BB 2
#define FDIM 2048
#define FH 64
#define FW 128
#define NPIX (FH*FW)        // 8192 pixels per (dom,b)
#define NC 19
#define SH 512
#define SW 1024

#define KS 4                // pixel splits per (d,b) plane
#define PXS (NPIX/KS)       // 2048 pixels per block (512 per wave)

// Workspace layout (bytes). psq+cnt+sum zeroed each launch (atomic accum).
#define OFF_PSQ   0                         // float psq[8][2][19]     = 1216 B (XCD partials)
#define OFF_CNT   1216                      // uint  cnt[2][19]        = 152 B
#define OFF_SUM   1408                      // float sum[2][19][2048]  = 311296 B
#define ZERO_BYTES 312704
#define OFF_LAB   312704                    // uchar labels[2][2][8192]= 32768 B
#define OFF_CENT  345472                    // float cent[19][2048]    = 155648 B
#define OFF_DOTS  501120                    // float dots[57]
#define OFF_ROW   501348                    // float row[19]

typedef __attribute__((ext_vector_type(8))) short short8v;   // 8 bf16 (4 VGPRs)
typedef __attribute__((ext_vector_type(4))) float f32x4;     // MFMA C/D

__device__ inline short f32_to_bf16_bits(float x) {
  __hip_bfloat16 h = __float2bfloat16(x);
  return *reinterpret_cast<short*>(&h);
}
__device__ inline float bf16_bits_to_f32(short s) {
  unsigned u = ((unsigned)s & 0xFFFFu) << 16;
  return __uint_as_float(u);
}

// ---------------------------------------------------------------------------
// Kernel 1: labels via align_corners bilinear downsample + argmax over C.
// 4 lanes per output pixel, shfl_xor argmax merge, first-max tie-break.
// Replicates jnp.linspace f32 arithmetic / mul-add association exactly.
// ---------------------------------------------------------------------------
__global__ __launch_bounds__(256) void labels_kernel(
    const float* __restrict__ sm_s, const float* __restrict__ sm_t,
    unsigned char* __restrict__ labels, unsigned int* __restrict__ cnt) {
  __shared__ unsigned int lcnt[NC];
  int tid = threadIdx.x;
  if (tid < NC) lcnt[tid] = 0u;
  __syncthreads();

  int g = blockIdx.x * 256 + tid;          // 0..131071
  int pixid = g >> 2;                      // 0..32767
  int sub = g & 3;
  int dom = pixid >> 14;                   // block-uniform
  int rem = pixid & 16383;
  int b   = rem >> 13;
  int pix = rem & (NPIX - 1);
  int oy  = pix >> 7;
  int ox  = pix & (FW - 1);

  const float* sm = dom ? sm_t : sm_s;

  const float step_y = 511.0f / 63.0f;
  const float step_x = 1023.0f / 127.0f;
  float fy = __fmul_rn((float)oy, step_y);
  float fx = __fmul_rn((float)ox, step_x);
  int y0 = (int)floorf(fy); int y1 = min(y0 + 1, SH - 1);
  int x0 = (int)floorf(fx); int x1 = min(x0 + 1, SW - 1);
  float wy = __fsub_rn(fy, (float)y0);
  float wx = __fsub_rn(fx, (float)x0);
  float omwy = __fsub_rn(1.0f, wy);
  float omwx = __fsub_rn(1.0f, wx);

  const float* base = sm + (size_t)b * (NC * SH * SW);
  float best = -1.0f; int bestc = 127;
  for (int c = sub; c < NC; c += 4) {
    const float* p = base + (size_t)c * (SH * SW);
    float v00 = p[y0 * SW + x0];
    float v01 = p[y0 * SW + x1];
    float v10 = p[y1 * SW + x0];
    float v11 = p[y1 * SW + x1];
    float r0  = __fadd_rn(__fmul_rn(v00, omwy), __fmul_rn(v10, wy));
    float r1  = __fadd_rn(__fmul_rn(v01, omwy), __fmul_rn(v11, wy));
    float val = __fadd_rn(__fmul_rn(r0, omwx), __fmul_rn(r1, wx));
    if (val > best) { best = val; bestc = c; }
  }
#pragma unroll
  for (int off = 1; off <= 2; off <<= 1) {
    float ov = __shfl_xor(best, off, 64);
    int   oc = __shfl_xor(bestc, off, 64);
    if (ov > best || (ov == best && oc < bestc)) { best = ov; bestc = oc; }
  }
  if (sub == 0) {
    labels[pixid] = (unsigned char)bestc;
    atomicAdd(&lcnt[bestc], 1u);
  }
  __syncthreads();
  if (tid < NC) atomicAdd(&cnt[dom * NC + tid], lcnt[tid]);
}

// ---------------------------------------------------------------------------
// Kernel 2 (hot): segment-sum as MFMA matmul, WAVE-PRIVATE pipelines.
// NO barriers in the main loop: each wave owns a private double-buffered
// [16][64] bf16 LDS tile and a private 512-px K-chunk. Per 64-px window:
//   issue 4 contiguous float4 loads (w+1) -> compute 2 MFMA K-steps (w)
//   -> cvt+ds_write (w+1).  Compiler emits counted per-use waits (no
//   barrier => no vmcnt(0) drains); waves drift out of phase so HBM
//   latency overlaps across ~16-28 resident waves/CU.
// Labels read directly from global (8B/K-step, L1-resident).
// bid encoding keeps atomic colliders of a sum-address on ONE XCD.
// ---------------------------------------------------------------------------
__global__ __launch_bounds__(256, 4) void segsum_kernel(
    const float* __restrict__ feat_s, const float* __restrict__ feat_t,
    const unsigned char* __restrict__ labels,
    float* __restrict__ sum, float* __restrict__ psq) {
  __shared__ unsigned short Abuf[4][2][16][64];   // 4 waves x dbuf x 2KB = 16KB

  int tid = threadIdx.x;
  int wv = tid >> 6, l = tid & 63;
  int m16 = l & 15, grp = l >> 4;
  int lrow = l >> 4;                       // sub-row 0..3 for staging
  int lpx  = (l & 15) * 4;                 // px offset 0..60 for staging

  // bid = (d*128 + strip) + 256*(ks*2 + b): colliders share bid%8 -> one XCD
  int low = blockIdx.x & 255;
  int hi  = blockIdx.x >> 8;               // 0..7
  int d = low >> 7, strip = low & 127;
  int b = hi & 1, ks = hi >> 1;

  const float* feat = d ? feat_t : feat_s;
  int px0 = ks * PXS + wv * 512;           // wave-private 512-px chunk
  const float* fbase = feat + ((size_t)(b * FDIM + strip * 16)) * NPIX + px0;
  const unsigned char* labp = labels + (d * 2 + b) * NPIX + px0;

  unsigned short (*mybuf)[16][64] = Abuf[wv];    // [2][16][64]

  f32x4 accS0 = {0.f,0.f,0.f,0.f}, accS1 = {0.f,0.f,0.f,0.f};
  f32x4 accQ0 = {0.f,0.f,0.f,0.f}, accQ1 = {0.f,0.f,0.f,0.f};

  float4 ld[4];

#define LOADW(W)                                                              \
  _Pragma("unroll") for (int r = 0; r < 4; ++r)                               \
    ld[r] = *(const float4*)(fbase + (size_t)(r * 4 + lrow) * NPIX +          \
                             (W) * 64 + lpx);

#define WRITEW(CUR)                                                           \
  _Pragma("unroll") for (int r = 0; r < 4; ++r) {                             \
    int row = r * 4 + lrow;                                                   \
    unsigned u0 = ((unsigned)(unsigned short)f32_to_bf16_bits(ld[r].x)) |     \
                  (((unsigned)(unsigned short)f32_to_bf16_bits(ld[r].y)) << 16);\
    unsigned u1 = ((unsigned)(unsigned short)f32_to_bf16_bits(ld[r].z)) |     \
                  (((unsigned)(unsigned short)f32_to_bf16_bits(ld[r].w)) << 16);\
    int wbyte = (row * 128 + lpx * 2) ^ ((row & 7) << 4);                     \
    *(uint2*)((char*)&mybuf[CUR][0][0] + wbyte) = make_uint2(u0, u1);         \
  }

  // prologue: window 0
  LOADW(0);
  WRITEW(0);

#pragma unroll 2
  for (int w = 0; w < 8; ++w) {
    int cur = w & 1;
    if (w < 7) { LOADW(w + 1); }           // issue early; write after compute
#pragma unroll
    for (int t = 0; t < 2; ++t) {
      int rbyte = (m16 * 128 + t * 64 + grp * 16) ^ ((m16 & 7) << 4);
      short8v a = *(const short8v*)((const char*)&mybuf[cur][0][0] + rbyte);
      short8v a2;
#pragma unroll
      for (int j = 0; j < 8; ++j) {
        float x = bf16_bits_to_f32(a[j]);
        a2[j] = f32_to_bf16_bits(x * x);
      }
      uint2 lw = *(const uint2*)(labp + w * 64 + t * 32 + grp * 8);
      short8v b0, b1;
#pragma unroll
      for (int j = 0; j < 8; ++j) {
        unsigned lab = ((j < 4 ? lw.x : lw.y) >> ((j & 3) * 8)) & 0xFFu;
        b0[j] = (lab == (unsigned)m16)        ? (short)0x3F80 : (short)0;
        b1[j] = (lab == (unsigned)(m16 + 16)) ? (short)0x3F80 : (short)0;
      }
      accS0 = __builtin_amdgcn_mfma_f32_16x16x32_bf16(a,  b0, accS0, 0, 0, 0);
      accS1 = __builtin_amdgcn_mfma_f32_16x16x32_bf16(a,  b1, accS1, 0, 0, 0);
      accQ0 = __builtin_amdgcn_mfma_f32_16x16x32_bf16(a2, b0, accQ0, 0, 0, 0);
      accQ1 = __builtin_amdgcn_mfma_f32_16x16x32_bf16(a2, b1, accQ1, 0, 0, 0);
    }
    if (w < 7) { WRITEW(cur ^ 1); }
  }
#undef LOADW
#undef WRITEW

  // ---- epilogue: barrier (Sred aliases Abuf), merge 4 waves, XCD-local atomics
  __syncthreads();
  float* Sred = (float*)&Abuf[0][0][0][0];   // [4][19][16] = 4864 B
  float* Qred = Sred + 4 * 19 * 16;          // [4][19]

  int c0 = l & 15, frb = (l >> 4) * 4;       // C/D: col=class, row=(l>>4)*4+reg
  *(f32x4*)&Sred[(wv * 19 + c0) * 16 + frb] = accS0;
  if (c0 < 3) *(f32x4*)&Sred[(wv * 19 + 16 + c0) * 16 + frb] = accS1;

  float q0 = accQ0[0] + accQ0[1] + accQ0[2] + accQ0[3];
  float q1 = accQ1[0] + accQ1[1] + accQ1[2] + accQ1[3];
  q0 += __shfl_xor(q0, 16, 64); q0 += __shfl_xor(q0, 32, 64);
  q1 += __shfl_xor(q1, 16, 64); q1 += __shfl_xor(q1, 32, 64);
  if (l < 16) Qred[wv * 19 + l] = q0;
  if (l < 3)  Qred[wv * 19 + 16 + l] = q1;
  __syncthreads();

  for (int t = tid; t < NC * 16; t += 256) {
    int c = t >> 4, fr = t & 15;
    float sv = Sred[(0 * 19 + c) * 16 + fr] + Sred[(1 * 19 + c) * 16 + fr] +
               Sred[(2 * 19 + c) * 16 + fr] + Sred[(3 * 19 + c) * 16 + fr];
    unsafeAtomicAdd(&sum[((size_t)d * NC + c) * FDIM + strip * 16 + fr], sv);
  }
  if (tid < NC) {
    float qv = Qred[tid] + Qred[19 + tid] + Qred[38 + tid] + Qred[57 + tid];
    unsafeAtomicAdd(&psq[(blockIdx.x & 7) * (2 * NC) + d * NC + tid], qv);
  }
}

// Block reduction helper (256 threads)
__device__ inline float block_reduce(float v, float* red, int tid) {
  red[tid] = v; __syncthreads();
  for (int s = 128; s > 0; s >>= 1) {
    if (tid < s) red[tid] += red[tid + s];
    __syncthreads();
  }
  float r = red[0];
  __syncthreads();
  return r;
}

// ---------------------------------------------------------------------------
// Kernel 3a: centroids + per-class dots.
// ---------------------------------------------------------------------------
__global__ __launch_bounds__(256) void centroid_kernel(
    const float* __restrict__ sum, const unsigned int* __restrict__ cnt,
    float* __restrict__ cent, float* __restrict__ dots) {
  __shared__ float red[256];
  int c = blockIdx.x;
  int tid = threadIdx.x;
  float cs = (float)cnt[c];
  float ct = (float)cnt[NC + c];
  float denom = fmaxf(cs + ct, 1.0f);
  float ds = 0.f, dt = 0.f, cc = 0.f;
  for (int f = tid; f < FDIM; f += 256) {
    float ssv = sum[(size_t)c * FDIM + f];
    float stv = sum[(size_t)(NC + c) * FDIM + f];
    float cf = (ssv + stv) / denom;
    cent[(size_t)c * FDIM + f] = cf;
    ds += cf * ssv; dt += cf * stv; cc += cf * cf;
  }
  float rds = block_reduce(ds, red, tid);
  float rdt = block_reduce(dt, red, tid);
  float rcc = block_reduce(cc, red, tid);
  if (tid == 0) {
    dots[c] = rds;
    dots[NC + c] = rdt;
    dots[2 * NC + c] = rcc;
  }
}

// ---------------------------------------------------------------------------
// Kernel 3b: row[i] = sum_{j != i, seen i&j} sum_f (c_i - c_j)^2
// ---------------------------------------------------------------------------
__global__ __launch_bounds__(256) void pair_kernel(
    const float* __restrict__ cent, const unsigned int* __restrict__ cnt,
    float* __restrict__ row) {
  __shared__ float red[256];
  int i = blockIdx.x;
  int tid = threadIdx.x;
  bool seen_i = (cnt[i] + cnt[NC + i]) > 0u;
  float acc = 0.f;
  if (seen_i) {
    for (int j = 0; j < NC; ++j) {
      if (j == i) continue;
      if ((cnt[j] + cnt[NC + j]) == 0u) continue;
      for (int f = tid; f < FDIM; f += 256) {
        float dd = cent[(size_t)i * FDIM + f] - cent[(size_t)j * FDIM + f];
        acc += dd * dd;
      }
    }
  }
  float r = block_reduce(acc, red, tid);
  if (tid == 0) row[i] = r;
}

// ---------------------------------------------------------------------------
// Kernel 3c: fold psq partials, assemble the 3 outputs (p == 2).
// One wave, lane c handles class c; ballot/popc + shfl_down trees.
// ---------------------------------------------------------------------------
__global__ void final_kernel(
    const unsigned int* __restrict__ cnt, const float* __restrict__ psq,
    const float* __restrict__ dots, const float* __restrict__ row,
    float* __restrict__ out) {
  int l = threadIdx.x;                      // one wave of 64
  const float fdim = (float)FDIM;
  bool isC = l < NC;
  int c = isC ? l : 0;

  float cs = 0.f, ct = 0.f, qs = 0.f, qt = 0.f;
  float d_s = 0.f, d_t = 0.f, cc = 0.f, rw = 0.f;
  if (isC) {
    cs = (float)cnt[c]; ct = (float)cnt[NC + c];
#pragma unroll
    for (int x = 0; x < 8; ++x) {           // 16 independent loads, all in flight
      qs += psq[x * (2 * NC) + c];
      qt += psq[x * (2 * NC) + NC + c];
    }
    d_s = dots[c]; d_t = dots[NC + c]; cc = dots[2 * NC + c];
    rw = row[c];
  }
  bool seen = isC && (cs + ct > 0.f);
  float nseenf = (float)__popcll(__ballot(seen));
  float nvs    = (float)__popcll(__ballot(isC && cs > 0.f));
  float nvt    = (float)__popcll(__ballot(isC && ct > 0.f));

  float fs = 0.f, ft = 0.f, cd = 0.f;
  if (isC && cs > 0.f) {
    float ssq = fmaxf(qs - 2.0f * d_s + cs * cc, 0.f);
    fs = sqrtf(ssq) / (cs * fdim);
  }
  if (isC && ct > 0.f) {
    float ssq = fmaxf(qt - 2.0f * d_t + ct * cc, 0.f);
    ft = sqrtf(ssq) / (ct * fdim);
  }
  if (seen) cd = sqrtf(rw) / ((nseenf - 1.0f) * fdim);

#pragma unroll
  for (int off = 32; off > 0; off >>= 1) {
    fs += __shfl_down(fs, off, 64);
    ft += __shfl_down(ft, off, 64);
    cd += __shfl_down(cd, off, 64);
  }
  if (l == 0) {
    out[0] = cd / nseenf;
    out[1] = fs / nvs;
    out[2] = ft / nvt;
  }
}

extern "C" void kernel_launch(void* const* d_in, const int* in_sizes, int n_in,
                              void* d_out, int out_size, void* d_ws, size_t ws_size,
                              hipStream_t stream) {
  const float* sfeat = (const float*)d_in[0];
  const float* ssm   = (const float*)d_in[1];
  const float* tfeat = (const float*)d_in[2];
  const float* tsm   = (const float*)d_in[3];
  float* out = (float*)d_out;

  char* ws = (char*)d_ws;
  float*         psq    = (float*)(ws + OFF_PSQ);
  unsigned int*  cnt    = (unsigned int*)(ws + OFF_CNT);
  float*         sum    = (float*)(ws + OFF_SUM);
  unsigned char* labels = (unsigned char*)(ws + OFF_LAB);
  float*         cent   = (float*)(ws + OFF_CENT);
  float*         dots   = (float*)(ws + OFF_DOTS);
  float*         row    = (float*)(ws + OFF_ROW);

  // zero psq+cnt+sum (atomic accumulators; graph replays need re-zeroing)
  hipMemsetAsync(ws, 0, ZERO_BYTES, stream);

  labels_kernel  <<<512,  256, 0, stream>>>(ssm, tsm, labels, cnt);
  segsum_kernel  <<<2048, 256, 0, stream>>>(sfeat, tfeat, labels, sum, psq);
  centroid_kernel<<<NC,   256, 0, stream>>>(sum, cnt, cent, dots);
  pair_kernel    <<<NC,   256, 0, stream>>>(cent, cnt, row);
  final_kernel   <<<1,    64,  0, stream>>>(cnt, psq, dots, row, out);
}